// Round 1
// baseline (1255.922 us; speedup 1.0000x reference)
//
#include <hip/hip_runtime.h>
#include <hip/hip_bf16.h>
#include <stdint.h>

// Problem constants (reference: T=10, N=2048, E=32768, H=256)
#define TT 10
#define NN 2048
#define EE 32768
#define HH 256

typedef short bf16x8 __attribute__((ext_vector_type(8)));
typedef float f32x4 __attribute__((ext_vector_type(4)));

__device__ __forceinline__ float b2f(unsigned short u) {
    unsigned int x = ((unsigned int)u) << 16;
    return __builtin_bit_cast(float, x);
}
__device__ __forceinline__ unsigned short f2b(float f) {
    unsigned int x = __builtin_bit_cast(unsigned int, f);
    unsigned int r = x + 0x7FFFu + ((x >> 16) & 1u);
    return (unsigned short)(r >> 16);
}

// ---------------- setup kernels ----------------

__global__ void cvt_bf16_kernel(const float* __restrict__ in,
                                unsigned short* __restrict__ out, int n) {
    int i = blockIdx.x * blockDim.x + threadIdx.x;
    int stride = gridDim.x * blockDim.x;
    for (; i < n; i += stride) out[i] = f2b(in[i]);
}

// W: [K][256] row-major (fan_in, fan_out) -> Wt: [256][KPAD] bf16, zero-padded
__global__ void transpose_w_kernel(const float* __restrict__ W,
                                   unsigned short* __restrict__ Wt, int K, int KPAD) {
    int idx = blockIdx.x * blockDim.x + threadIdx.x;
    if (idx >= 256 * KPAD) return;
    int n = idx / KPAD, k = idx - n * KPAD;
    Wt[idx] = (k < K) ? f2b(W[k * 256 + n]) : (unsigned short)0;
}

__global__ void zero_f32_kernel(float* __restrict__ p, int n) {
    int i = blockIdx.x * blockDim.x + threadIdx.x;
    int stride = gridDim.x * blockDim.x;
    for (; i < n; i += stride) p[i] = 0.0f;
}

__global__ void count_kernel(const int* __restrict__ rows, int* __restrict__ counts) {
    int e = blockIdx.x * blockDim.x + threadIdx.x;
    if (e < EE) atomicAdd(&counts[rows[e]], 1);
}

// ---------------- per-t kernels ----------------

// One wave per edge: build edge_in[e][544] = [h[row](256), h[col](256), radial(16), pad(16)]
// and cdiff[e][12] = x[row]-x[col].
__global__ __launch_bounds__(256) void gather_kernel(
    const float* __restrict__ xt, const unsigned short* __restrict__ hbt,
    const int* __restrict__ rows, const int* __restrict__ cols,
    unsigned short* __restrict__ edge_in, float* __restrict__ cdiff) {
    int w = threadIdx.x >> 6, lane = threadIdx.x & 63;
    int e = blockIdx.x * 4 + w;
    int r = rows[e], c = cols[e];

    const ushort4* hr = reinterpret_cast<const ushort4*>(hbt + (size_t)r * HH);
    const ushort4* hc = reinterpret_cast<const ushort4*>(hbt + (size_t)c * HH);
    ushort4* dst = reinterpret_cast<ushort4*>(edge_in + (size_t)e * 544);
    dst[lane] = hr[lane];        // cols 0..255
    dst[64 + lane] = hc[lane];   // cols 256..511

    if (lane < 12) {
        cdiff[(size_t)e * 12 + lane] = xt[r * 12 + lane] - xt[c * 12 + lane];
    }
    // gram[j][k] on lanes 0..15
    float g = 0.f;
    if (lane < 16) {
        int j = lane >> 2, kk = lane & 3;
        for (int d = 0; d < 3; ++d) {
            float a = xt[r * 12 + j * 3 + d] - xt[c * 12 + j * 3 + d];
            float b = xt[r * 12 + kk * 3 + d] - xt[c * 12 + kk * 3 + d];
            g += a * b;
        }
    }
    float ss = g * g;
    ss += __shfl_xor(ss, 1);
    ss += __shfl_xor(ss, 2);
    ss += __shfl_xor(ss, 4);
    ss += __shfl_xor(ss, 8);
    float denom = fmaxf(sqrtf(ss), 1e-12f);
    if (lane < 16) {
        edge_in[(size_t)e * 544 + 512 + lane] = f2b(g / denom);
        edge_in[(size_t)e * 544 + 528 + lane] = 0;
    }
}

// C[M,256] = act(A[M,KPAD] @ Wt[256,KPAD]^T + bias), 64x64 block tile, 4 waves.
// EPI 0: store bf16. EPI 1: store bf16 + atomicAdd into aggf[rows[m]*256+col].
// EPI 2: store f32 out = v + resid (no relu expected).
template<int EPI, bool RELU>
__global__ __launch_bounds__(256) void gemm_kernel(
    const unsigned short* __restrict__ A, const unsigned short* __restrict__ Wt,
    const float* __restrict__ bias, unsigned short* __restrict__ Cb, int KPAD,
    const int* __restrict__ rows, float* __restrict__ aggf,
    const float* __restrict__ resid, float* __restrict__ outf) {
    __shared__ unsigned short As[64][40];
    __shared__ unsigned short Ws[64][40];
    int tid = threadIdx.x;
    int lane = tid & 63, w = tid >> 6;
    int wr = w >> 1, wc = w & 1;
    int blockRow = blockIdx.x * 64, colBase = blockIdx.y * 64;
    int lrow = lane & 15, kg = lane >> 4;

    f32x4 acc[2][2] = {};
    int rowA = tid >> 2, cg = (tid & 3) * 8;

    for (int k0 = 0; k0 < KPAD; k0 += 32) {
        uint4 va = *reinterpret_cast<const uint4*>(A + (size_t)(blockRow + rowA) * KPAD + k0 + cg);
        uint4 vb = *reinterpret_cast<const uint4*>(Wt + (size_t)(colBase + rowA) * KPAD + k0 + cg);
        *reinterpret_cast<uint4*>(&As[rowA][cg]) = va;
        *reinterpret_cast<uint4*>(&Ws[rowA][cg]) = vb;
        __syncthreads();
        bf16x8 af0 = *reinterpret_cast<const bf16x8*>(&As[wr * 32 + lrow][kg * 8]);
        bf16x8 af1 = *reinterpret_cast<const bf16x8*>(&As[wr * 32 + 16 + lrow][kg * 8]);
        bf16x8 bf0 = *reinterpret_cast<const bf16x8*>(&Ws[wc * 32 + lrow][kg * 8]);
        bf16x8 bf1 = *reinterpret_cast<const bf16x8*>(&Ws[wc * 32 + 16 + lrow][kg * 8]);
        acc[0][0] = __builtin_amdgcn_mfma_f32_16x16x32_bf16(af0, bf0, acc[0][0], 0, 0, 0);
        acc[0][1] = __builtin_amdgcn_mfma_f32_16x16x32_bf16(af0, bf1, acc[0][1], 0, 0, 0);
        acc[1][0] = __builtin_amdgcn_mfma_f32_16x16x32_bf16(af1, bf0, acc[1][0], 0, 0, 0);
        acc[1][1] = __builtin_amdgcn_mfma_f32_16x16x32_bf16(af1, bf1, acc[1][1], 0, 0, 0);
        __syncthreads();
    }

    for (int fi = 0; fi < 2; ++fi) {
        for (int fj = 0; fj < 2; ++fj) {
            int col = colBase + wc * 32 + fj * 16 + lrow;
            float bv = bias[col];
            for (int r = 0; r < 4; ++r) {
                int row = blockRow + wr * 32 + fi * 16 + kg * 4 + r;
                float v = acc[fi][fj][r] + bv;
                if (RELU) v = fmaxf(v, 0.f);
                if (EPI == 2) {
                    outf[(size_t)row * 256 + col] = v + resid[(size_t)row * 256 + col];
                } else {
                    Cb[(size_t)row * 256 + col] = f2b(v);
                    if (EPI == 1) {
                        int node = rows[row];
                        atomicAdd(&aggf[node * 256 + col], v);
                    }
                }
            }
        }
    }
}

// m[e] = Y3[e,:] . Wc2 ; then atomicAdd coord sums: csum[rows[e]*12+i] += cdiff[e][i]*m
__global__ __launch_bounds__(256) void gemv_coord_kernel(
    const unsigned short* __restrict__ Y3, const float* __restrict__ Wc2,
    const int* __restrict__ rows, const float* __restrict__ cdiff,
    float* __restrict__ csum) {
    int w = threadIdx.x >> 6, lane = threadIdx.x & 63;
    int e = blockIdx.x * 4 + w;
    ushort4 y = reinterpret_cast<const ushort4*>(Y3 + (size_t)e * 256)[lane];
    int c0 = lane * 4;
    float p = b2f(y.x) * Wc2[c0] + b2f(y.y) * Wc2[c0 + 1] +
              b2f(y.z) * Wc2[c0 + 2] + b2f(y.w) * Wc2[c0 + 3];
    p += __shfl_xor(p, 1);
    p += __shfl_xor(p, 2);
    p += __shfl_xor(p, 4);
    p += __shfl_xor(p, 8);
    p += __shfl_xor(p, 16);
    p += __shfl_xor(p, 32);
    if (lane < 12) {
        atomicAdd(&csum[rows[e] * 12 + lane], cdiff[(size_t)e * 12 + lane] * p);
    }
}

// node_in[n][768] = [others(256), h(256), agg(256)] as bf16
__global__ void nodein_kernel(const unsigned short* __restrict__ obt,
                              const unsigned short* __restrict__ hbt,
                              const float* __restrict__ aggf,
                              unsigned short* __restrict__ node_in) {
    int idx = blockIdx.x * blockDim.x + threadIdx.x;
    if (idx >= NN * 768) return;
    int n = idx / 768, c = idx - n * 768;
    unsigned short v;
    if (c < 256) v = obt[n * 256 + c];
    else if (c < 512) v = hbt[n * 256 + (c - 256)];
    else v = f2b(aggf[n * 256 + (c - 512)]);
    node_in[idx] = v;
}

__global__ void coordout_kernel(const float* __restrict__ xt, const int* __restrict__ counts,
                                const float* __restrict__ csum, float* __restrict__ outc) {
    int idx = blockIdx.x * blockDim.x + threadIdx.x;
    if (idx >= NN * 12) return;
    int n = idx / 12;
    float cnt = (float)(counts[n] > 0 ? counts[n] : 1);
    outc[idx] = xt[idx] + csum[idx] / cnt;
}

// ---------------- launch ----------------

extern "C" void kernel_launch(void* const* d_in, const int* in_sizes, int n_in,
                              void* d_out, int out_size, void* d_ws, size_t ws_size,
                              hipStream_t stream) {
    const float* x = (const float*)d_in[0];
    const float* h = (const float*)d_in[1];
    const float* others = (const float*)d_in[2];
    const float* We1 = (const float*)d_in[3];
    const float* be1 = (const float*)d_in[4];
    const float* We2 = (const float*)d_in[5];
    const float* be2 = (const float*)d_in[6];
    const float* Wn1 = (const float*)d_in[7];
    const float* bn1 = (const float*)d_in[8];
    const float* Wn2 = (const float*)d_in[9];
    const float* bn2 = (const float*)d_in[10];
    const float* Wc1 = (const float*)d_in[11];
    const float* bc1 = (const float*)d_in[12];
    const float* Wc2 = (const float*)d_in[13];
    const int* ei = (const int*)d_in[14];
    const int* rows = ei;
    const int* cols = ei + EE;

    char* wsb = (char*)d_ws;
    size_t off = 0;
    auto alloc = [&](size_t bytes) {
        void* p = wsb + off;
        off = (off + bytes + 255) & ~(size_t)255;
        return p;
    };
    const int TNH = TT * NN * HH;
    unsigned short* hb = (unsigned short*)alloc((size_t)TNH * 2);
    unsigned short* ob = (unsigned short*)alloc((size_t)TNH * 2);
    unsigned short* We1t = (unsigned short*)alloc(256 * 544 * 2);
    unsigned short* We2t = (unsigned short*)alloc(256 * 256 * 2);
    unsigned short* Wn1t = (unsigned short*)alloc(256 * 768 * 2);
    unsigned short* Wn2t = (unsigned short*)alloc(256 * 256 * 2);
    unsigned short* Wc1t = (unsigned short*)alloc(256 * 256 * 2);
    unsigned short* edge_in = (unsigned short*)alloc((size_t)EE * 544 * 2);
    unsigned short* Y1 = (unsigned short*)alloc((size_t)EE * 256 * 2);
    unsigned short* e_buf = (unsigned short*)alloc((size_t)EE * 256 * 2);
    float* cdiff = (float*)alloc((size_t)EE * 12 * 4);
    float* aggf = (float*)alloc((size_t)NN * 256 * 4);   // contiguous with csum
    float* csum = (float*)alloc((size_t)NN * 12 * 4);
    int* counts = (int*)alloc((size_t)NN * 4);
    unsigned short* node_in = (unsigned short*)alloc((size_t)NN * 768 * 2);
    unsigned short* Z = (unsigned short*)alloc((size_t)NN * 256 * 2);
    unsigned short* Y3 = edge_in;  // alias: edge_in dead after GEMM1 within a t

    // ---- setup ----
    cvt_bf16_kernel<<<4096, 256, 0, stream>>>(h, hb, TNH);
    cvt_bf16_kernel<<<4096, 256, 0, stream>>>(others, ob, TNH);
    transpose_w_kernel<<<544, 256, 0, stream>>>(We1, We1t, 528, 544);
    transpose_w_kernel<<<256, 256, 0, stream>>>(We2, We2t, 256, 256);
    transpose_w_kernel<<<768, 256, 0, stream>>>(Wn1, Wn1t, 768, 768);
    transpose_w_kernel<<<256, 256, 0, stream>>>(Wn2, Wn2t, 256, 256);
    transpose_w_kernel<<<256, 256, 0, stream>>>(Wc1, Wc1t, 256, 256);
    zero_f32_kernel<<<8, 256, 0, stream>>>((float*)counts, NN);
    count_kernel<<<EE / 256, 256, 0, stream>>>(rows, counts);

    float* houtf = (float*)d_out;
    float* coutf = (float*)d_out + (size_t)TT * NN * HH;

    for (int t = 0; t < TT; ++t) {
        const float* xt = x + (size_t)t * NN * 12;
        const unsigned short* hbt = hb + (size_t)t * NN * HH;
        const unsigned short* obt = ob + (size_t)t * NN * HH;
        const float* ht = h + (size_t)t * NN * HH;

        zero_f32_kernel<<<512, 256, 0, stream>>>(aggf, NN * 256 + NN * 12);

        gather_kernel<<<EE / 4, 256, 0, stream>>>(xt, hbt, rows, cols, edge_in, cdiff);

        gemm_kernel<0, true><<<dim3(EE / 64, 4), 256, 0, stream>>>(
            edge_in, We1t, be1, Y1, 544, nullptr, nullptr, nullptr, nullptr);
        gemm_kernel<1, true><<<dim3(EE / 64, 4), 256, 0, stream>>>(
            Y1, We2t, be2, e_buf, 256, rows, aggf, nullptr, nullptr);
        gemm_kernel<0, true><<<dim3(EE / 64, 4), 256, 0, stream>>>(
            e_buf, Wc1t, bc1, Y3, 256, nullptr, nullptr, nullptr, nullptr);

        gemv_coord_kernel<<<EE / 4, 256, 0, stream>>>(Y3, Wc2, rows, cdiff, csum);

        nodein_kernel<<<(NN * 768 + 255) / 256, 256, 0, stream>>>(obt, hbt, aggf, node_in);

        gemm_kernel<0, true><<<dim3(NN / 64, 4), 256, 0, stream>>>(
            node_in, Wn1t, bn1, Z, 768, nullptr, nullptr, nullptr, nullptr);
        gemm_kernel<2, false><<<dim3(NN / 64, 4), 256, 0, stream>>>(
            Z, Wn2t, bn2, nullptr, 256, nullptr, nullptr, ht, houtf + (size_t)t * NN * HH);

        coordout_kernel<<<(NN * 12 + 255) / 256, 256, 0, stream>>>(
            xt, counts, csum, coutf + (size_t)t * NN * 12);
    }
}

// Round 2
// 1106.281 us; speedup vs baseline: 1.1353x; 1.1353x over previous
//
#include <hip/hip_runtime.h>
#include <hip/hip_bf16.h>
#include <stdint.h>

// Problem constants (reference: T=10, N=2048, E=32768, H=256)
#define TT 10
#define NN 2048
#define EE 32768
#define HH 256

typedef short bf16x8 __attribute__((ext_vector_type(8)));
typedef float f32x4 __attribute__((ext_vector_type(4)));

__device__ __forceinline__ float b2f(unsigned short u) {
    unsigned int x = ((unsigned int)u) << 16;
    return __builtin_bit_cast(float, x);
}
__device__ __forceinline__ unsigned short f2b(float f) {
    unsigned int x = __builtin_bit_cast(unsigned int, f);
    unsigned int r = x + 0x7FFFu + ((x >> 16) & 1u);
    return (unsigned short)(r >> 16);
}

#define GLOAD_LDS16(g, l)                                                      \
    __builtin_amdgcn_global_load_lds(                                          \
        (const __attribute__((address_space(1))) void*)(g),                    \
        (__attribute__((address_space(3))) void*)(l), 16, 0, 0)

// ---------------- setup kernels ----------------

__global__ void cvt_bf16_kernel(const float* __restrict__ in,
                                unsigned short* __restrict__ out, int n) {
    int i = blockIdx.x * blockDim.x + threadIdx.x;
    int stride = gridDim.x * blockDim.x;
    for (; i < n; i += stride) out[i] = f2b(in[i]);
}

// W: [K][256] row-major (fan_in, fan_out) -> Wt: [256][KPAD] bf16, zero-padded
__global__ void transpose_w_kernel(const float* __restrict__ W,
                                   unsigned short* __restrict__ Wt, int K, int KPAD) {
    int idx = blockIdx.x * blockDim.x + threadIdx.x;
    if (idx >= 256 * KPAD) return;
    int n = idx / KPAD, k = idx - n * KPAD;
    Wt[idx] = (k < K) ? f2b(W[k * 256 + n]) : (unsigned short)0;
}

__global__ void zero_f32_kernel(float* __restrict__ p, int n) {
    int i = blockIdx.x * blockDim.x + threadIdx.x;
    int stride = gridDim.x * blockDim.x;
    for (; i < n; i += stride) p[i] = 0.0f;
}

__global__ void count_kernel(const int* __restrict__ rows, int* __restrict__ counts) {
    int e = blockIdx.x * blockDim.x + threadIdx.x;
    if (e < EE) atomicAdd(&counts[rows[e]], 1);
}

// ---------------- per-t kernels ----------------

// 16 lanes per edge: cdiff[e][12] = x[row]-x[col]; radial32[e][0..15] = normalized
// gram, [16..31] = 0 (zero-padded K-tail for the fused edge GEMM).
__global__ __launch_bounds__(256) void radial_kernel(
    const float* __restrict__ xt, const int* __restrict__ rows,
    const int* __restrict__ cols, unsigned short* __restrict__ radial32,
    float* __restrict__ cdiff) {
    int tid = threadIdx.x;
    int e = blockIdx.x * 16 + (tid >> 4);
    int l16 = tid & 15;
    int r = rows[e], c = cols[e];

    int j = l16 >> 2, kk = l16 & 3;
    float g = 0.f;
    for (int d = 0; d < 3; ++d) {
        float a = xt[r * 12 + j * 3 + d] - xt[c * 12 + j * 3 + d];
        float b = xt[r * 12 + kk * 3 + d] - xt[c * 12 + kk * 3 + d];
        g += a * b;
    }
    float ss = g * g;
    ss += __shfl_xor(ss, 1);
    ss += __shfl_xor(ss, 2);
    ss += __shfl_xor(ss, 4);
    ss += __shfl_xor(ss, 8);
    float denom = fmaxf(sqrtf(ss), 1e-12f);
    radial32[(size_t)e * 32 + l16] = f2b(g / denom);
    radial32[(size_t)e * 32 + 16 + l16] = 0;
    if (l16 < 12) {
        cdiff[(size_t)e * 12 + l16] = xt[r * 12 + l16] - xt[c * 12 + l16];
    }
}

// m97-structure GEMM: C[M,256] = relu(A[M,KPAD] @ Wt[256,KPAD]^T + bias) as bf16.
// 128x128 tile, BK=32, 4 waves (2x2), each wave 64x64 (4x4 MFMA frags).
// GATHER: A sourced from h[row]|h[col]|radial32 segments (K = 256|256|32).
// EPI 1: additionally atomicAdd into aggf[rowIdx[m]*256+col].
template<int EPI, bool GATHER>
__global__ __launch_bounds__(256) void gemm128_kernel(
    const unsigned short* __restrict__ A, const unsigned short* __restrict__ Wt,
    const float* __restrict__ bias, unsigned short* __restrict__ Cb, int KPAD,
    const unsigned short* __restrict__ hbt, const unsigned short* __restrict__ radial32,
    const int* __restrict__ rowIdx, const int* __restrict__ colIdx,
    float* __restrict__ aggf) {
    __shared__ unsigned short As[128 * 32];
    __shared__ unsigned short Bs[128 * 32];
    int tid = threadIdx.x;
    int lane = tid & 63, w = tid >> 6;
    int wr = w >> 1, wc = w & 1;
    int blockRow = blockIdx.x * 128, colBase = blockIdx.y * 128;
    int l4 = lane >> 2;   // row within 16-row chunk
    int seg = lane & 3;   // which 16B (8 bf16) segment of the 32-wide row

    int ar0 = blockRow + w * 16 + l4;   // A rows this thread stages
    int ar1 = ar0 + 64;
    int br0 = colBase + w * 16 + l4;    // Wt rows (output cols)
    int br1 = br0 + 64;

    const unsigned short *pB0 = Wt + (size_t)br0 * KPAD + seg * 8;
    const unsigned short *pB1 = Wt + (size_t)br1 * KPAD + seg * 8;

    const unsigned short *hr0, *hc0, *rd0, *hr1, *hc1, *rd1;
    const unsigned short *pA0, *pA1;
    if (GATHER) {
        int r0 = rowIdx[ar0], c0 = colIdx[ar0];
        int r1 = rowIdx[ar1], c1 = colIdx[ar1];
        hr0 = hbt + (size_t)r0 * 256 + seg * 8;
        hc0 = hbt + (size_t)c0 * 256 + seg * 8 - 256;
        rd0 = radial32 + (size_t)ar0 * 32 + seg * 8 - 512;
        hr1 = hbt + (size_t)r1 * 256 + seg * 8;
        hc1 = hbt + (size_t)c1 * 256 + seg * 8 - 256;
        rd1 = radial32 + (size_t)ar1 * 32 + seg * 8 - 512;
    } else {
        pA0 = A + (size_t)ar0 * KPAD + seg * 8;
        pA1 = A + (size_t)ar1 * KPAD + seg * 8;
    }

    unsigned short* ldsA = As + w * 512;   // wave-uniform base (bytes: w*1024)
    unsigned short* ldsB = Bs + w * 512;

    f32x4 acc[4][4] = {};
    int lr = lane & 15, lq = lane >> 4;

    for (int k0 = 0; k0 < KPAD; k0 += 32) {
        const unsigned short *sA0, *sA1;
        if (GATHER) {
            sA0 = (k0 < 256) ? hr0 + k0 : (k0 < 512) ? hc0 + k0 : rd0 + k0;
            sA1 = (k0 < 256) ? hr1 + k0 : (k0 < 512) ? hc1 + k0 : rd1 + k0;
        } else {
            sA0 = pA0 + k0;
            sA1 = pA1 + k0;
        }
        GLOAD_LDS16(sA0, ldsA);
        GLOAD_LDS16(sA1, ldsA + 2048);
        GLOAD_LDS16(pB0 + k0, ldsB);
        GLOAD_LDS16(pB1 + k0, ldsB + 2048);
        __syncthreads();   // drains vmcnt before use

        bf16x8 a[4], b[4];
#pragma unroll
        for (int m = 0; m < 4; ++m)
            a[m] = *reinterpret_cast<const bf16x8*>(
                As + (wr * 64 + m * 16 + lr) * 32 + lq * 8);
#pragma unroll
        for (int n = 0; n < 4; ++n)
            b[n] = *reinterpret_cast<const bf16x8*>(
                Bs + (wc * 64 + n * 16 + lr) * 32 + lq * 8);
#pragma unroll
        for (int m = 0; m < 4; ++m)
#pragma unroll
            for (int n = 0; n < 4; ++n)
                acc[m][n] = __builtin_amdgcn_mfma_f32_16x16x32_bf16(
                    a[m], b[n], acc[m][n], 0, 0, 0);
        __syncthreads();
    }

    float bv[4];
#pragma unroll
    for (int n = 0; n < 4; ++n) bv[n] = bias[colBase + wc * 64 + n * 16 + lr];

#pragma unroll
    for (int m = 0; m < 4; ++m) {
#pragma unroll
        for (int r = 0; r < 4; ++r) {
            int row = blockRow + wr * 64 + m * 16 + lq * 4 + r;
            int node = (EPI == 1) ? rowIdx[row] : 0;
#pragma unroll
            for (int n = 0; n < 4; ++n) {
                int col = colBase + wc * 64 + n * 16 + lr;
                float v = fmaxf(acc[m][n][r] + bv[n], 0.f);
                Cb[(size_t)row * 256 + col] = f2b(v);
                if (EPI == 1) atomicAdd(&aggf[node * 256 + col], v);
            }
        }
    }
}

// Small-M GEMM for node MLPs (64x64 tile). EPI 0: bf16+relu. EPI 2: f32 out = v+resid.
template<int EPI, bool RELU>
__global__ __launch_bounds__(256) void gemm_kernel(
    const unsigned short* __restrict__ A, const unsigned short* __restrict__ Wt,
    const float* __restrict__ bias, unsigned short* __restrict__ Cb, int KPAD,
    const float* __restrict__ resid, float* __restrict__ outf) {
    __shared__ unsigned short As[64][40];
    __shared__ unsigned short Ws[64][40];
    int tid = threadIdx.x;
    int lane = tid & 63, w = tid >> 6;
    int wr = w >> 1, wc = w & 1;
    int blockRow = blockIdx.x * 64, colBase = blockIdx.y * 64;
    int lrow = lane & 15, kg = lane >> 4;

    f32x4 acc[2][2] = {};
    int rowA = tid >> 2, cg = (tid & 3) * 8;

    for (int k0 = 0; k0 < KPAD; k0 += 32) {
        uint4 va = *reinterpret_cast<const uint4*>(A + (size_t)(blockRow + rowA) * KPAD + k0 + cg);
        uint4 vb = *reinterpret_cast<const uint4*>(Wt + (size_t)(colBase + rowA) * KPAD + k0 + cg);
        *reinterpret_cast<uint4*>(&As[rowA][cg]) = va;
        *reinterpret_cast<uint4*>(&Ws[rowA][cg]) = vb;
        __syncthreads();
        bf16x8 af0 = *reinterpret_cast<const bf16x8*>(&As[wr * 32 + lrow][kg * 8]);
        bf16x8 af1 = *reinterpret_cast<const bf16x8*>(&As[wr * 32 + 16 + lrow][kg * 8]);
        bf16x8 bf0 = *reinterpret_cast<const bf16x8*>(&Ws[wc * 32 + lrow][kg * 8]);
        bf16x8 bf1 = *reinterpret_cast<const bf16x8*>(&Ws[wc * 32 + 16 + lrow][kg * 8]);
        acc[0][0] = __builtin_amdgcn_mfma_f32_16x16x32_bf16(af0, bf0, acc[0][0], 0, 0, 0);
        acc[0][1] = __builtin_amdgcn_mfma_f32_16x16x32_bf16(af0, bf1, acc[0][1], 0, 0, 0);
        acc[1][0] = __builtin_amdgcn_mfma_f32_16x16x32_bf16(af1, bf0, acc[1][0], 0, 0, 0);
        acc[1][1] = __builtin_amdgcn_mfma_f32_16x16x32_bf16(af1, bf1, acc[1][1], 0, 0, 0);
        __syncthreads();
    }

    for (int fi = 0; fi < 2; ++fi) {
        for (int fj = 0; fj < 2; ++fj) {
            int col = colBase + wc * 32 + fj * 16 + lrow;
            float bvv = bias[col];
            for (int r = 0; r < 4; ++r) {
                int row = blockRow + wr * 32 + fi * 16 + kg * 4 + r;
                float v = acc[fi][fj][r] + bvv;
                if (RELU) v = fmaxf(v, 0.f);
                if (EPI == 2) {
                    outf[(size_t)row * 256 + col] = v + resid[(size_t)row * 256 + col];
                } else {
                    Cb[(size_t)row * 256 + col] = f2b(v);
                }
            }
        }
    }
}

// m[e] = Y3[e,:] . Wc2 ; then atomicAdd coord sums: csum[rows[e]*12+i] += cdiff[e][i]*m
__global__ __launch_bounds__(256) void gemv_coord_kernel(
    const unsigned short* __restrict__ Y3, const float* __restrict__ Wc2,
    const int* __restrict__ rows, const float* __restrict__ cdiff,
    float* __restrict__ csum) {
    int w = threadIdx.x >> 6, lane = threadIdx.x & 63;
    int e = blockIdx.x * 4 + w;
    ushort4 y = reinterpret_cast<const ushort4*>(Y3 + (size_t)e * 256)[lane];
    int c0 = lane * 4;
    float p = b2f(y.x) * Wc2[c0] + b2f(y.y) * Wc2[c0 + 1] +
              b2f(y.z) * Wc2[c0 + 2] + b2f(y.w) * Wc2[c0 + 3];
    p += __shfl_xor(p, 1);
    p += __shfl_xor(p, 2);
    p += __shfl_xor(p, 4);
    p += __shfl_xor(p, 8);
    p += __shfl_xor(p, 16);
    p += __shfl_xor(p, 32);
    if (lane < 12) {
        atomicAdd(&csum[rows[e] * 12 + lane], cdiff[(size_t)e * 12 + lane] * p);
    }
}

// node_in[n][768] = [others(256), h(256), agg(256)] as bf16
__global__ void nodein_kernel(const unsigned short* __restrict__ obt,
                              const unsigned short* __restrict__ hbt,
                              const float* __restrict__ aggf,
                              unsigned short* __restrict__ node_in) {
    int idx = blockIdx.x * blockDim.x + threadIdx.x;
    if (idx >= NN * 768) return;
    int n = idx / 768, c = idx - n * 768;
    unsigned short v;
    if (c < 256) v = obt[n * 256 + c];
    else if (c < 512) v = hbt[n * 256 + (c - 256)];
    else v = f2b(aggf[n * 256 + (c - 512)]);
    node_in[idx] = v;
}

__global__ void coordout_kernel(const float* __restrict__ xt, const int* __restrict__ counts,
                                const float* __restrict__ csum, float* __restrict__ outc) {
    int idx = blockIdx.x * blockDim.x + threadIdx.x;
    if (idx >= NN * 12) return;
    int n = idx / 12;
    float cnt = (float)(counts[n] > 0 ? counts[n] : 1);
    outc[idx] = xt[idx] + csum[idx] / cnt;
}

// ---------------- launch ----------------

extern "C" void kernel_launch(void* const* d_in, const int* in_sizes, int n_in,
                              void* d_out, int out_size, void* d_ws, size_t ws_size,
                              hipStream_t stream) {
    const float* x = (const float*)d_in[0];
    const float* h = (const float*)d_in[1];
    const float* others = (const float*)d_in[2];
    const float* We1 = (const float*)d_in[3];
    const float* be1 = (const float*)d_in[4];
    const float* We2 = (const float*)d_in[5];
    const float* be2 = (const float*)d_in[6];
    const float* Wn1 = (const float*)d_in[7];
    const float* bn1 = (const float*)d_in[8];
    const float* Wn2 = (const float*)d_in[9];
    const float* bn2 = (const float*)d_in[10];
    const float* Wc1 = (const float*)d_in[11];
    const float* bc1 = (const float*)d_in[12];
    const float* Wc2 = (const float*)d_in[13];
    const int* ei = (const int*)d_in[14];
    const int* rows = ei;
    const int* cols = ei + EE;

    char* wsb = (char*)d_ws;
    size_t off = 0;
    auto alloc = [&](size_t bytes) {
        void* p = wsb + off;
        off = (off + bytes + 255) & ~(size_t)255;
        return p;
    };
    const int TNH = TT * NN * HH;
    unsigned short* hb = (unsigned short*)alloc((size_t)TNH * 2);
    unsigned short* ob = (unsigned short*)alloc((size_t)TNH * 2);
    unsigned short* We1t = (unsigned short*)alloc(256 * 544 * 2);
    unsigned short* We2t = (unsigned short*)alloc(256 * 256 * 2);
    unsigned short* Wn1t = (unsigned short*)alloc(256 * 768 * 2);
    unsigned short* Wn2t = (unsigned short*)alloc(256 * 256 * 2);
    unsigned short* Wc1t = (unsigned short*)alloc(256 * 256 * 2);
    unsigned short* radial32 = (unsigned short*)alloc((size_t)EE * 32 * 2);
    unsigned short* Y1 = (unsigned short*)alloc((size_t)EE * 256 * 2);
    unsigned short* e_buf = (unsigned short*)alloc((size_t)EE * 256 * 2);
    unsigned short* Y3 = (unsigned short*)alloc((size_t)EE * 256 * 2);
    float* cdiff = (float*)alloc((size_t)EE * 12 * 4);
    float* aggf = (float*)alloc((size_t)NN * 256 * 4);   // contiguous with csum
    float* csum = (float*)alloc((size_t)NN * 12 * 4);
    int* counts = (int*)alloc((size_t)NN * 4);
    unsigned short* node_in = (unsigned short*)alloc((size_t)NN * 768 * 2);
    unsigned short* Z = (unsigned short*)alloc((size_t)NN * 256 * 2);

    // ---- setup ----
    cvt_bf16_kernel<<<4096, 256, 0, stream>>>(h, hb, TNH);
    cvt_bf16_kernel<<<4096, 256, 0, stream>>>(others, ob, TNH);
    transpose_w_kernel<<<544, 256, 0, stream>>>(We1, We1t, 528, 544);
    transpose_w_kernel<<<256, 256, 0, stream>>>(We2, We2t, 256, 256);
    transpose_w_kernel<<<768, 256, 0, stream>>>(Wn1, Wn1t, 768, 768);
    transpose_w_kernel<<<256, 256, 0, stream>>>(Wn2, Wn2t, 256, 256);
    transpose_w_kernel<<<256, 256, 0, stream>>>(Wc1, Wc1t, 256, 256);
    zero_f32_kernel<<<8, 256, 0, stream>>>((float*)counts, NN);
    count_kernel<<<EE / 256, 256, 0, stream>>>(rows, counts);

    float* houtf = (float*)d_out;
    float* coutf = (float*)d_out + (size_t)TT * NN * HH;

    for (int t = 0; t < TT; ++t) {
        const float* xt = x + (size_t)t * NN * 12;
        const unsigned short* hbt = hb + (size_t)t * NN * HH;
        const unsigned short* obt = ob + (size_t)t * NN * HH;
        const float* ht = h + (size_t)t * NN * HH;

        zero_f32_kernel<<<512, 256, 0, stream>>>(aggf, NN * 256 + NN * 12);

        radial_kernel<<<EE / 16, 256, 0, stream>>>(xt, rows, cols, radial32, cdiff);

        // edge_mlp layer 1 (K=544, gathered A), layer 2 (+agg atomics), coord_mlp l1
        gemm128_kernel<0, true><<<dim3(EE / 128, 2), 256, 0, stream>>>(
            nullptr, We1t, be1, Y1, 544, hbt, radial32, rows, cols, nullptr);
        gemm128_kernel<1, false><<<dim3(EE / 128, 2), 256, 0, stream>>>(
            Y1, We2t, be2, e_buf, 256, nullptr, nullptr, rows, nullptr, aggf);
        gemm128_kernel<0, false><<<dim3(EE / 128, 2), 256, 0, stream>>>(
            e_buf, Wc1t, bc1, Y3, 256, nullptr, nullptr, nullptr, nullptr, nullptr);

        gemv_coord_kernel<<<EE / 4, 256, 0, stream>>>(Y3, Wc2, rows, cdiff, csum);

        nodein_kernel<<<(NN * 768 + 255) / 256, 256, 0, stream>>>(obt, hbt, aggf, node_in);

        gemm_kernel<0, true><<<dim3(NN / 64, 4), 256, 0, stream>>>(
            node_in, Wn1t, bn1, Z, 768, nullptr, nullptr);
        gemm_kernel<2, false><<<dim3(NN / 64, 4), 256, 0, stream>>>(
            Z, Wn2t, bn2, nullptr, 256, ht, houtf + (size_t)t * NN * HH);

        coordout_kernel<<<(NN * 12 + 255) / 256, 256, 0, stream>>>(
            xt, counts, csum, coutf + (size_t)t * NN * 12);
    }
}

// Round 3
// 784.335 us; speedup vs baseline: 1.6013x; 1.4105x over previous
//
#include <hip/hip_runtime.h>
#include <hip/hip_bf16.h>
#include <stdint.h>

// Problem constants (reference: T=10, N=2048, E=32768, H=256)
#define TT 10
#define NN 2048
#define EE 32768
#define HH 256

typedef short bf16x8 __attribute__((ext_vector_type(8)));
typedef float f32x4 __attribute__((ext_vector_type(4)));

__device__ __forceinline__ float b2f(unsigned short u) {
    unsigned int x = ((unsigned int)u) << 16;
    return __builtin_bit_cast(float, x);
}
__device__ __forceinline__ unsigned short f2b(float f) {
    unsigned int x = __builtin_bit_cast(unsigned int, f);
    unsigned int r = x + 0x7FFFu + ((x >> 16) & 1u);
    return (unsigned short)(r >> 16);
}

#define GLOAD_LDS16(g, l)                                                      \
    __builtin_amdgcn_global_load_lds(                                          \
        (const __attribute__((address_space(1))) void*)(g),                    \
        (__attribute__((address_space(3))) void*)(l), 16, 0, 0)

// ---------------- setup kernels ----------------

__global__ void cvt_bf16_kernel(const float* __restrict__ in,
                                unsigned short* __restrict__ out, int n) {
    int i = blockIdx.x * blockDim.x + threadIdx.x;
    int stride = gridDim.x * blockDim.x;
    for (; i < n; i += stride) out[i] = f2b(in[i]);
}

// W: [K][256] row-major (fan_in, fan_out) -> Wt: [256][KPAD] bf16, zero-padded
__global__ void transpose_w_kernel(const float* __restrict__ W,
                                   unsigned short* __restrict__ Wt, int K, int KPAD) {
    int idx = blockIdx.x * blockDim.x + threadIdx.x;
    if (idx >= 256 * KPAD) return;
    int n = idx / KPAD, k = idx - n * KPAD;
    Wt[idx] = (k < K) ? f2b(W[k * 256 + n]) : (unsigned short)0;
}

__global__ void zero_f32_kernel(float* __restrict__ p, int n) {
    int i = blockIdx.x * blockDim.x + threadIdx.x;
    int stride = gridDim.x * blockDim.x;
    for (; i < n; i += stride) p[i] = 0.0f;
}

__global__ void count_kernel(const int* __restrict__ rows, int* __restrict__ counts) {
    int e = blockIdx.x * blockDim.x + threadIdx.x;
    if (e < EE) atomicAdd(&counts[rows[e]], 1);
}

// ---------------- per-chunk kernels ----------------

// 16 lanes per edge-instance (t,e): radial32[el][0..15]=normalized gram,
// [16..31]=0; cdiff[el][12] = x[t,row]-x[t,col].  el = chunk-local t*EE+e.
__global__ __launch_bounds__(256) void radial_kernel(
    const float* __restrict__ x, const int* __restrict__ rows,
    const int* __restrict__ cols, unsigned short* __restrict__ radial32,
    float* __restrict__ cdiff, int tbase) {
    int tid = threadIdx.x;
    int el = blockIdx.x * 16 + (tid >> 4);
    int l16 = tid & 15;
    int e = el & (EE - 1);
    int t = tbase + (el >> 15);
    const float* xt = x + (size_t)t * NN * 12;
    int r = rows[e], c = cols[e];

    int j = l16 >> 2, kk = l16 & 3;
    float g = 0.f;
    for (int d = 0; d < 3; ++d) {
        float a = xt[r * 12 + j * 3 + d] - xt[c * 12 + j * 3 + d];
        float b = xt[r * 12 + kk * 3 + d] - xt[c * 12 + kk * 3 + d];
        g += a * b;
    }
    float ss = g * g;
    ss += __shfl_xor(ss, 1);
    ss += __shfl_xor(ss, 2);
    ss += __shfl_xor(ss, 4);
    ss += __shfl_xor(ss, 8);
    float denom = fmaxf(sqrtf(ss), 1e-12f);
    radial32[(size_t)el * 32 + l16] = f2b(g / denom);
    radial32[(size_t)el * 32 + 16 + l16] = 0;
    if (l16 < 12) {
        cdiff[(size_t)el * 12 + l16] = xt[r * 12 + l16] - xt[c * 12 + l16];
    }
}

// m97-structure GEMM: 128x128 tile, BK=32, 4 waves (2x2), wave = 64x64 (4x4 frags).
// A is [M][KPAD] bf16 (or GATHERed from hb|hb|radial32 with K = 256|256|32).
// EPI 0: relu -> bf16 store.
// EPI 1: relu -> bf16 store + atomicAdd aggf[node(row)][col].
// EPI 2: (no relu) f32 store outf = acc + bias + resid.
// EPI 3: relu -> dot with Wc2[col], 16-lane reduce, atomicAdd m_e[row]. No store.
template<int EPI, bool GATHER>
__global__ __launch_bounds__(256) void gemm128_kernel(
    const unsigned short* __restrict__ A, const unsigned short* __restrict__ Wt,
    const float* __restrict__ bias, unsigned short* __restrict__ Cb, int KPAD,
    const unsigned short* __restrict__ hb, const unsigned short* __restrict__ radial32,
    const int* __restrict__ rows, const int* __restrict__ cols,
    float* __restrict__ aggf, const float* __restrict__ Wc2, float* __restrict__ m_e,
    const float* __restrict__ resid, float* __restrict__ outf, int tbase) {
    __shared__ unsigned short As[128 * 32];
    __shared__ unsigned short Bs[128 * 32];
    int tid = threadIdx.x;
    int lane = tid & 63, w = tid >> 6;
    int wr = w >> 1, wc = w & 1;
    int blockRow = blockIdx.x * 128, colBase = blockIdx.y * 128;
    int l4 = lane >> 2;   // row within 16-row chunk
    int seg = lane & 3;   // which 16B (8 bf16) segment of the 32-wide row

    int ar0 = blockRow + w * 16 + l4;   // A rows this thread stages
    int ar1 = ar0 + 64;
    int br0 = colBase + w * 16 + l4;    // Wt rows (output cols)
    int br1 = br0 + 64;

    const unsigned short *pB0 = Wt + (size_t)br0 * KPAD + seg * 8;
    const unsigned short *pB1 = Wt + (size_t)br1 * KPAD + seg * 8;

    const unsigned short *hr0, *hc0, *rd0, *hr1, *hc1, *rd1;
    const unsigned short *pA0, *pA1;
    if (GATHER) {
        int e0 = ar0 & (EE - 1), t0 = tbase + (ar0 >> 15);
        int e1 = ar1 & (EE - 1), t1 = tbase + (ar1 >> 15);
        size_t n0r = ((size_t)(t0 << 11) + rows[e0]) * 256;
        size_t n0c = ((size_t)(t0 << 11) + cols[e0]) * 256;
        size_t n1r = ((size_t)(t1 << 11) + rows[e1]) * 256;
        size_t n1c = ((size_t)(t1 << 11) + cols[e1]) * 256;
        hr0 = hb + n0r + seg * 8;
        hc0 = hb + n0c + seg * 8 - 256;
        rd0 = radial32 + (size_t)ar0 * 32 + seg * 8 - 512;
        hr1 = hb + n1r + seg * 8;
        hc1 = hb + n1c + seg * 8 - 256;
        rd1 = radial32 + (size_t)ar1 * 32 + seg * 8 - 512;
    } else {
        pA0 = A + (size_t)ar0 * KPAD + seg * 8;
        pA1 = A + (size_t)ar1 * KPAD + seg * 8;
    }

    unsigned short* ldsA = As + w * 512;   // wave-uniform base
    unsigned short* ldsB = Bs + w * 512;

    f32x4 acc[4][4] = {};
    int lr = lane & 15, lq = lane >> 4;

    for (int k0 = 0; k0 < KPAD; k0 += 32) {
        const unsigned short *sA0, *sA1;
        if (GATHER) {
            sA0 = (k0 < 256) ? hr0 + k0 : (k0 < 512) ? hc0 + k0 : rd0 + k0;
            sA1 = (k0 < 256) ? hr1 + k0 : (k0 < 512) ? hc1 + k0 : rd1 + k0;
        } else {
            sA0 = pA0 + k0;
            sA1 = pA1 + k0;
        }
        GLOAD_LDS16(sA0, ldsA);
        GLOAD_LDS16(sA1, ldsA + 2048);
        GLOAD_LDS16(pB0 + k0, ldsB);
        GLOAD_LDS16(pB1 + k0, ldsB + 2048);
        __syncthreads();   // drains vmcnt before use

        bf16x8 a[4], b[4];
#pragma unroll
        for (int m = 0; m < 4; ++m)
            a[m] = *reinterpret_cast<const bf16x8*>(
                As + (wr * 64 + m * 16 + lr) * 32 + lq * 8);
#pragma unroll
        for (int n = 0; n < 4; ++n)
            b[n] = *reinterpret_cast<const bf16x8*>(
                Bs + (wc * 64 + n * 16 + lr) * 32 + lq * 8);
#pragma unroll
        for (int m = 0; m < 4; ++m)
#pragma unroll
            for (int n = 0; n < 4; ++n)
                acc[m][n] = __builtin_amdgcn_mfma_f32_16x16x32_bf16(
                    a[m], b[n], acc[m][n], 0, 0, 0);
        __syncthreads();
    }

    float bv[4], wv[4];
#pragma unroll
    for (int n = 0; n < 4; ++n) {
        int col = colBase + wc * 64 + n * 16 + lr;
        bv[n] = bias[col];
        if (EPI == 3) wv[n] = Wc2[col];
    }

#pragma unroll
    for (int m = 0; m < 4; ++m) {
#pragma unroll
        for (int r = 0; r < 4; ++r) {
            int row = blockRow + wr * 64 + m * 16 + lq * 4 + r;
            if (EPI == 3) {
                float p = 0.f;
#pragma unroll
                for (int n = 0; n < 4; ++n)
                    p += fmaxf(acc[m][n][r] + bv[n], 0.f) * wv[n];
                p += __shfl_xor(p, 1);
                p += __shfl_xor(p, 2);
                p += __shfl_xor(p, 4);
                p += __shfl_xor(p, 8);
                if (lr == 0) atomicAdd(&m_e[row], p);
            } else {
                int node = 0;
                if (EPI == 1)
                    node = ((tbase + (row >> 15)) << 11) + rows[row & (EE - 1)];
#pragma unroll
                for (int n = 0; n < 4; ++n) {
                    int col = colBase + wc * 64 + n * 16 + lr;
                    float v = acc[m][n][r] + bv[n];
                    if (EPI == 0 || EPI == 1) v = fmaxf(v, 0.f);
                    if (EPI == 2) {
                        outf[(size_t)row * 256 + col] =
                            v + resid[(size_t)row * 256 + col];
                    } else {
                        Cb[(size_t)row * 256 + col] = f2b(v);
                        if (EPI == 1) atomicAdd(&aggf[(size_t)node * 256 + col], v);
                    }
                }
            }
        }
    }
}

// csum[t][rows[e]][i] += cdiff[el][i] * m_e[el]
__global__ void coord_scatter_kernel(const int* __restrict__ rows,
                                     const float* __restrict__ cdiff,
                                     const float* __restrict__ m_e,
                                     float* __restrict__ csum, int tbase, int total) {
    int idx = blockIdx.x * blockDim.x + threadIdx.x;
    int stride = gridDim.x * blockDim.x;
    for (; idx < total; idx += stride) {
        int el = idx / 12, i = idx - el * 12;
        int e = el & (EE - 1);
        int t = tbase + (el >> 15);
        atomicAdd(&csum[((size_t)t * NN + rows[e]) * 12 + i],
                  cdiff[(size_t)idx] * m_e[el]);
    }
}

// node_in[nf][768] = [others(256), h(256), agg(256)] bf16, nf = t*N+n; 4 elems/thread
__global__ void nodein_kernel(const unsigned short* __restrict__ ob,
                              const unsigned short* __restrict__ hb,
                              const float* __restrict__ aggf,
                              unsigned short* __restrict__ node_in) {
    int idx = blockIdx.x * blockDim.x + threadIdx.x;
    int stride = gridDim.x * blockDim.x;
    const int total = TT * NN * 192;
    for (; idx < total; idx += stride) {
        int nf = idx / 192, c4 = (idx - nf * 192) * 4;
        ushort4 v;
        if (c4 < 256) {
            v = *reinterpret_cast<const ushort4*>(ob + (size_t)nf * 256 + c4);
        } else if (c4 < 512) {
            v = *reinterpret_cast<const ushort4*>(hb + (size_t)nf * 256 + (c4 - 256));
        } else {
            float4 a = *reinterpret_cast<const float4*>(aggf + (size_t)nf * 256 + (c4 - 512));
            v.x = f2b(a.x); v.y = f2b(a.y); v.z = f2b(a.z); v.w = f2b(a.w);
        }
        *reinterpret_cast<ushort4*>(node_in + (size_t)nf * 768 + c4) = v;
    }
}

__global__ void coordout_kernel(const float* __restrict__ x, const int* __restrict__ counts,
                                const float* __restrict__ csum, float* __restrict__ outc) {
    int idx = blockIdx.x * blockDim.x + threadIdx.x;
    if (idx >= TT * NN * 12) return;
    int n = (idx / 12) & (NN - 1);
    float cnt = (float)(counts[n] > 0 ? counts[n] : 1);
    outc[idx] = x[idx] + csum[idx] / cnt;
}

// ---------------- launch ----------------

extern "C" void kernel_launch(void* const* d_in, const int* in_sizes, int n_in,
                              void* d_out, int out_size, void* d_ws, size_t ws_size,
                              hipStream_t stream) {
    const float* x = (const float*)d_in[0];
    const float* h = (const float*)d_in[1];
    const float* others = (const float*)d_in[2];
    const float* We1 = (const float*)d_in[3];
    const float* be1 = (const float*)d_in[4];
    const float* We2 = (const float*)d_in[5];
    const float* be2 = (const float*)d_in[6];
    const float* Wn1 = (const float*)d_in[7];
    const float* bn1 = (const float*)d_in[8];
    const float* Wn2 = (const float*)d_in[9];
    const float* bn2 = (const float*)d_in[10];
    const float* Wc1 = (const float*)d_in[11];
    const float* bc1 = (const float*)d_in[12];
    const float* Wc2 = (const float*)d_in[13];
    const int* ei = (const int*)d_in[14];
    const int* rows = ei;
    const int* cols = ei + EE;

    char* wsb = (char*)d_ws;
    size_t off = 0;
    auto alloc = [&](size_t bytes) {
        void* p = wsb + off;
        off = (off + bytes + 255) & ~(size_t)255;
        return p;
    };
    const int TNH = TT * NN * HH;
    // ---- fixed allocations ----
    unsigned short* hb = (unsigned short*)alloc((size_t)TNH * 2);
    unsigned short* ob = (unsigned short*)alloc((size_t)TNH * 2);
    unsigned short* We1t = (unsigned short*)alloc(256 * 544 * 2);
    unsigned short* We2t = (unsigned short*)alloc(256 * 256 * 2);
    unsigned short* Wn1t = (unsigned short*)alloc(256 * 768 * 2);
    unsigned short* Wn2t = (unsigned short*)alloc(256 * 256 * 2);
    unsigned short* Wc1t = (unsigned short*)alloc(256 * 256 * 2);
    float* aggf = (float*)alloc((size_t)TT * NN * 256 * 4);  // contiguous zero region:
    float* csum = (float*)alloc((size_t)TT * NN * 12 * 4);   // aggf | csum | counts
    int* counts = (int*)alloc((size_t)NN * 4);
    unsigned short* node_in = (unsigned short*)alloc((size_t)TT * NN * 768 * 2);
    unsigned short* Z = (unsigned short*)alloc((size_t)TT * NN * 256 * 2);

    // ---- chunked allocations: pick largest TC in {10,5,2,1} that fits ----
    int TC = 1;
    {
        const int cand[4] = {10, 5, 2, 1};
        for (int i = 0; i < 4; ++i) {
            size_t c = (size_t)cand[i] * EE;
            size_t need = 2 * (c * 256 * 2 + 256)   // Y1, e_buf
                        + (c * 32 * 2 + 256)        // radial32
                        + (c * 12 * 4 + 256)        // cdiff
                        + (c * 4 + 256);            // m_e
            if (off + need <= ws_size) { TC = cand[i]; break; }
        }
    }
    const int cM = TC * EE;  // chunk M
    unsigned short* Y1 = (unsigned short*)alloc((size_t)cM * 256 * 2);
    unsigned short* e_buf = (unsigned short*)alloc((size_t)cM * 256 * 2);
    unsigned short* radial32 = (unsigned short*)alloc((size_t)cM * 32 * 2);
    float* cdiff = (float*)alloc((size_t)cM * 12 * 4);
    float* m_e = (float*)alloc((size_t)cM * 4);

    // ---- setup ----
    cvt_bf16_kernel<<<2048, 256, 0, stream>>>(h, hb, TNH);
    cvt_bf16_kernel<<<2048, 256, 0, stream>>>(others, ob, TNH);
    transpose_w_kernel<<<544, 256, 0, stream>>>(We1, We1t, 528, 544);
    transpose_w_kernel<<<256, 256, 0, stream>>>(We2, We2t, 256, 256);
    transpose_w_kernel<<<768, 256, 0, stream>>>(Wn1, Wn1t, 768, 768);
    transpose_w_kernel<<<256, 256, 0, stream>>>(Wn2, Wn2t, 256, 256);
    transpose_w_kernel<<<256, 256, 0, stream>>>(Wc1, Wc1t, 256, 256);
    zero_f32_kernel<<<2048, 256, 0, stream>>>(
        aggf, TT * NN * 256 + TT * NN * 12 + NN);  // aggf+csum+counts contiguous
    count_kernel<<<EE / 256, 256, 0, stream>>>(rows, counts);

    float* houtf = (float*)d_out;
    float* coutf = (float*)d_out + (size_t)TT * NN * HH;

    // ---- edge pipeline, chunked over timesteps ----
    for (int tbase = 0; tbase < TT; tbase += TC) {
        radial_kernel<<<cM / 16, 256, 0, stream>>>(x, rows, cols, radial32, cdiff, tbase);
        zero_f32_kernel<<<512, 256, 0, stream>>>(m_e, cM);

        gemm128_kernel<0, true><<<dim3(cM / 128, 2), 256, 0, stream>>>(
            nullptr, We1t, be1, Y1, 544, hb, radial32, rows, cols,
            nullptr, nullptr, nullptr, nullptr, nullptr, tbase);
        gemm128_kernel<1, false><<<dim3(cM / 128, 2), 256, 0, stream>>>(
            Y1, We2t, be2, e_buf, 256, nullptr, nullptr, rows, nullptr,
            aggf, nullptr, nullptr, nullptr, nullptr, tbase);
        gemm128_kernel<3, false><<<dim3(cM / 128, 2), 256, 0, stream>>>(
            e_buf, Wc1t, bc1, nullptr, 256, nullptr, nullptr, nullptr, nullptr,
            nullptr, Wc2, m_e, nullptr, nullptr, tbase);

        coord_scatter_kernel<<<1024, 256, 0, stream>>>(rows, cdiff, m_e, csum,
                                                       tbase, cM * 12);
    }

    // ---- node pipeline, all timesteps at once ----
    nodein_kernel<<<2048, 256, 0, stream>>>(ob, hb, aggf, node_in);
    gemm128_kernel<0, false><<<dim3(TT * NN / 128, 2), 256, 0, stream>>>(
        node_in, Wn1t, bn1, Z, 768, nullptr, nullptr, nullptr, nullptr,
        nullptr, nullptr, nullptr, nullptr, nullptr, 0);
    gemm128_kernel<2, false><<<dim3(TT * NN / 128, 2), 256, 0, stream>>>(
        Z, Wn2t, bn2, nullptr, 256, nullptr, nullptr, nullptr, nullptr,
        nullptr, nullptr, nullptr, h, houtf, 0);

    coordout_kernel<<<(TT * NN * 12 + 255) / 256, 256, 0, stream>>>(
        x, counts, csum, coutf);
}

// Round 4
// 642.615 us; speedup vs baseline: 1.9544x; 1.2205x over previous
//
#include <hip/hip_runtime.h>
#include <hip/hip_bf16.h>
#include <stdint.h>

// Problem constants (reference: T=10, N=2048, E=32768, H=256)
#define TT 10
#define NN 2048
#define EE 32768
#define HH 256

typedef short bf16x8 __attribute__((ext_vector_type(8)));
typedef float f32x4 __attribute__((ext_vector_type(4)));

__device__ __forceinline__ float b2f(unsigned short u) {
    unsigned int x = ((unsigned int)u) << 16;
    return __builtin_bit_cast(float, x);
}
__device__ __forceinline__ unsigned short f2b(float f) {
    unsigned int x = __builtin_bit_cast(unsigned int, f);
    unsigned int r = x + 0x7FFFu + ((x >> 16) & 1u);
    return (unsigned short)(r >> 16);
}

#define GLOAD_LDS16(g, l)                                                      \
    __builtin_amdgcn_global_load_lds(                                          \
        (const __attribute__((address_space(1))) void*)(g),                    \
        (__attribute__((address_space(3))) void*)(l), 16, 0, 0)

// ---------------- setup kernels ----------------

__global__ void cvt_bf16_kernel(const float* __restrict__ in,
                                unsigned short* __restrict__ out, int n) {
    int i = blockIdx.x * blockDim.x + threadIdx.x;
    int stride = gridDim.x * blockDim.x;
    for (; i < n; i += stride) out[i] = f2b(in[i]);
}

// W: [K][256] row-major -> Wt: [256][KPAD] bf16, zero-padded
__global__ void transpose_w_kernel(const float* __restrict__ W,
                                   unsigned short* __restrict__ Wt, int K, int KPAD) {
    int idx = blockIdx.x * blockDim.x + threadIdx.x;
    if (idx >= 256 * KPAD) return;
    int n = idx / KPAD, k = idx - n * KPAD;
    Wt[idx] = (k < K) ? f2b(W[k * 256 + n]) : (unsigned short)0;
}

__global__ void zero_f32_kernel(float* __restrict__ p, int n) {
    int i = blockIdx.x * blockDim.x + threadIdx.x;
    int stride = gridDim.x * blockDim.x;
    for (; i < n; i += stride) p[i] = 0.0f;
}

__global__ void count_kernel(const int* __restrict__ rows, int* __restrict__ counts) {
    int e = blockIdx.x * blockDim.x + threadIdx.x;
    if (e < EE) atomicAdd(&counts[rows[e]], 1);
}

// ---------------- edge megakernel helpers ----------------

// Stage B tile [256][64] bf16 into Bs via global_load_lds; LDS stays linear,
// the XOR-swizzle is applied on the SOURCE kseg (rule: gload_lds dest is
// wave-uniform base + lane*16). LDS[row][kseg*8..] = logical[row][(kseg^(row&7))*8..].
__device__ __forceinline__ void stageB(const unsigned short* __restrict__ Wt,
                                       int KPAD, int k0, int tid, int w,
                                       unsigned short* Bs) {
    int trow = tid >> 3;
    int sk8 = ((tid & 7) ^ (trow & 7)) * 8;
#pragma unroll
    for (int i = 0; i < 8; ++i) {
        int row = i * 32 + trow;
        GLOAD_LDS16(Wt + (size_t)row * KPAD + k0 + sk8, Bs + i * 2048 + w * 512);
    }
}

// One BK=64 MFMA step; A from As[64][64], B from Bs[256][64], both stored with
// per-row XOR swizzle; read with phys = (col) ^ ((row&7)<<3).
__device__ __forceinline__ void mfma_step(const unsigned short* As,
                                          const unsigned short* Bs,
                                          int w, int lr, int lq, f32x4 acc[4][4]) {
    int xs = (lr & 7) << 3;
#pragma unroll
    for (int kk = 0; kk < 64; kk += 32) {
        bf16x8 a[4], b[4];
        int pc = (kk + lq * 8) ^ xs;
#pragma unroll
        for (int m = 0; m < 4; ++m)
            a[m] = *reinterpret_cast<const bf16x8*>(As + (m * 16 + lr) * 64 + pc);
#pragma unroll
        for (int n = 0; n < 4; ++n)
            b[n] = *reinterpret_cast<const bf16x8*>(
                Bs + (w * 64 + n * 16 + lr) * 64 + pc);
#pragma unroll
        for (int m = 0; m < 4; ++m)
#pragma unroll
            for (int n = 0; n < 4; ++n)
                acc[m][n] = __builtin_amdgcn_mfma_f32_16x16x32_bf16(
                    a[m], b[n], acc[m][n], 0, 0, 0);
    }
}

// Same but A from Es[64][256] (swizzled, element phys = col ^ ((row&7)<<3)).
__device__ __forceinline__ void mfma_step_es(const unsigned short* Es,
                                             const unsigned short* Bs, int k0,
                                             int w, int lr, int lq, f32x4 acc[4][4]) {
    int xs = (lr & 7) << 3;
#pragma unroll
    for (int kk = 0; kk < 64; kk += 32) {
        bf16x8 a[4], b[4];
        int lcol = kk + lq * 8;
#pragma unroll
        for (int m = 0; m < 4; ++m)
            a[m] = *reinterpret_cast<const bf16x8*>(
                Es + (m * 16 + lr) * 256 + ((k0 + lcol) ^ xs));
#pragma unroll
        for (int n = 0; n < 4; ++n)
            b[n] = *reinterpret_cast<const bf16x8*>(
                Bs + (w * 64 + n * 16 + lr) * 64 + (lcol ^ xs));
#pragma unroll
        for (int m = 0; m < 4; ++m)
#pragma unroll
            for (int n = 0; n < 4; ++n)
                acc[m][n] = __builtin_amdgcn_mfma_f32_16x16x32_bf16(
                    a[m], b[n], acc[m][n], 0, 0, 0);
    }
}

// ---------------- edge megakernel ----------------
// Per block: 64 edge-instances (rows). Phases:
//  0) compute cdiff + radial for own rows (LDS CDs, Rs)
//  1) GEMM1: E1 = relu([h[row]|h[col]|radial] @ We1t^T + be1)   K=576 -> Es
//  2) GEMM2: E2 = relu(E1 @ We2t^T + be2)                       K=256 -> Es
//  3) GEMM3: m = relu(E2 @ Wc1t^T + bc1) . Wc2                  K=256
//  epilogue: csum atomics (cdiff*m), agg atomics (E2 from Es).
__global__ __launch_bounds__(256, 2) void edge_mega_kernel(
    const float* __restrict__ x, const unsigned short* __restrict__ hb,
    const unsigned short* __restrict__ We1t, const float* __restrict__ be1,
    const unsigned short* __restrict__ We2t, const float* __restrict__ be2,
    const unsigned short* __restrict__ Wc1t, const float* __restrict__ bc1,
    const float* __restrict__ Wc2,
    const int* __restrict__ rows, const int* __restrict__ cols,
    float* __restrict__ aggf, float* __restrict__ csum) {
    __shared__ unsigned short As[64 * 64];    // 8 KB
    __shared__ unsigned short Bs[256 * 64];   // 32 KB
    __shared__ unsigned short Es[64 * 256];   // 32 KB (swizzled)
    __shared__ float CDs[64][12];             // 3 KB
    __shared__ unsigned short Rs[64][16];     // 2 KB
    __shared__ float Ms[64][4];               // 1 KB

    int tid = threadIdx.x;
    int lane = tid & 63, w = tid >> 6;
    int lr = lane & 15, lq = lane >> 4;
    int blockRow = blockIdx.x * 64;
    int tt = blockRow >> 15;                  // timestep (64 | 32768 -> uniform)

    // ---- phase 0: radial + cdiff for this block's 64 edges ----
    if (tid < 64) {
        int e = (blockRow + tid) & (EE - 1);
        int r = rows[e], c = cols[e];
        const float* xr = x + ((size_t)tt * NN + r) * 12;
        const float* xc = x + ((size_t)tt * NN + c) * 12;
        float cd[12];
#pragma unroll
        for (int i = 0; i < 12; ++i) {
            cd[i] = xr[i] - xc[i];
            CDs[tid][i] = cd[i];
        }
        float g[16], ss = 0.f;
#pragma unroll
        for (int j = 0; j < 4; ++j)
#pragma unroll
            for (int k = 0; k < 4; ++k) {
                float v = cd[j * 3] * cd[k * 3] + cd[j * 3 + 1] * cd[k * 3 + 1] +
                          cd[j * 3 + 2] * cd[k * 3 + 2];
                g[j * 4 + k] = v;
                ss += v * v;
            }
        float inv = 1.f / fmaxf(sqrtf(ss), 1e-12f);
#pragma unroll
        for (int i = 0; i < 16; ++i) Rs[tid][i] = f2b(g[i] * inv);
    }

    // gather source pointers for phase 1 A-staging
    int trow = tid >> 3;
    int sk8 = ((tid & 7) ^ (trow & 7)) * 8;
    const unsigned short *hr0, *hc0, *hr1, *hc1;
    {
        int e0 = (blockRow + trow) & (EE - 1);
        int e1 = (blockRow + 32 + trow) & (EE - 1);
        hr0 = hb + ((size_t)tt * NN + rows[e0]) * 256 + sk8;
        hc0 = hb + ((size_t)tt * NN + cols[e0]) * 256 + sk8 - 256;
        hr1 = hb + ((size_t)tt * NN + rows[e1]) * 256 + sk8;
        hc1 = hb + ((size_t)tt * NN + cols[e1]) * 256 + sk8 - 256;
    }

    __syncthreads();  // Rs/CDs ready

    f32x4 acc[4][4];
#pragma unroll
    for (int m = 0; m < 4; ++m)
#pragma unroll
        for (int n = 0; n < 4; ++n) acc[m][n] = (f32x4){0.f, 0.f, 0.f, 0.f};

    // ---- phase 1: K = 0..511 from h gathers, tail 512..575 from Rs ----
#pragma unroll 1
    for (int k0 = 0; k0 < 512; k0 += 64) {
        const unsigned short* s0 = (k0 < 256) ? hr0 + k0 : hc0 + k0;
        const unsigned short* s1 = (k0 < 256) ? hr1 + k0 : hc1 + k0;
        GLOAD_LDS16(s0, As + w * 512);
        GLOAD_LDS16(s1, As + 2048 + w * 512);
        stageB(We1t, 576, k0, tid, w, Bs);
        __syncthreads();
        mfma_step(As, Bs, w, lr, lq, acc);
        __syncthreads();
    }
    {   // radial tail step (k0 = 512): fill As from Rs via ds_write
#pragma unroll
        for (int j = 0; j < 2; ++j) {
            int row = j * 32 + trow;
            int lseg = (tid & 7) ^ (row & 7);
            bf16x8 v = {};
            if (lseg < 2) {
#pragma unroll
                for (int ii = 0; ii < 8; ++ii)
                    v[ii] = (short)Rs[row][lseg * 8 + ii];
            }
            *reinterpret_cast<bf16x8*>(As + row * 64 + (tid & 7) * 8) = v;
        }
        stageB(We1t, 576, 512, tid, w, Bs);
        __syncthreads();
        mfma_step(As, Bs, w, lr, lq, acc);
        __syncthreads();
    }
    {   // epilogue 1: relu + bias -> Es (swizzled bf16)
        float bv[4];
#pragma unroll
        for (int n = 0; n < 4; ++n) bv[n] = be1[w * 64 + n * 16 + lr];
#pragma unroll
        for (int m = 0; m < 4; ++m)
#pragma unroll
            for (int r = 0; r < 4; ++r) {
                int row = m * 16 + lq * 4 + r;
                int xsw = (row & 7) << 3;
#pragma unroll
                for (int n = 0; n < 4; ++n) {
                    int col = w * 64 + n * 16 + lr;
                    float v = fmaxf(acc[m][n][r] + bv[n], 0.f);
                    Es[row * 256 + (col ^ xsw)] = f2b(v);
                }
            }
    }
    __syncthreads();

    // ---- phase 2: E2 = relu(E1 @ We2t^T + be2) ----
#pragma unroll
    for (int m = 0; m < 4; ++m)
#pragma unroll
        for (int n = 0; n < 4; ++n) acc[m][n] = (f32x4){0.f, 0.f, 0.f, 0.f};
#pragma unroll 1
    for (int k0 = 0; k0 < 256; k0 += 64) {
        stageB(We2t, 256, k0, tid, w, Bs);
        __syncthreads();
        mfma_step_es(Es, Bs, k0, w, lr, lq, acc);
        __syncthreads();
    }
    {   // epilogue 2: overwrite Es with E2 (reads all done at trailing barrier)
        float bv[4];
#pragma unroll
        for (int n = 0; n < 4; ++n) bv[n] = be2[w * 64 + n * 16 + lr];
#pragma unroll
        for (int m = 0; m < 4; ++m)
#pragma unroll
            for (int r = 0; r < 4; ++r) {
                int row = m * 16 + lq * 4 + r;
                int xsw = (row & 7) << 3;
#pragma unroll
                for (int n = 0; n < 4; ++n) {
                    int col = w * 64 + n * 16 + lr;
                    float v = fmaxf(acc[m][n][r] + bv[n], 0.f);
                    Es[row * 256 + (col ^ xsw)] = f2b(v);
                }
            }
    }
    __syncthreads();

    // ---- phase 3: m = relu(E2 @ Wc1t^T + bc1) . Wc2 ----
#pragma unroll
    for (int m = 0; m < 4; ++m)
#pragma unroll
        for (int n = 0; n < 4; ++n) acc[m][n] = (f32x4){0.f, 0.f, 0.f, 0.f};
#pragma unroll 1
    for (int k0 = 0; k0 < 256; k0 += 64) {
        stageB(Wc1t, 256, k0, tid, w, Bs);
        __syncthreads();
        mfma_step_es(Es, Bs, k0, w, lr, lq, acc);
        __syncthreads();
    }
    {   // epilogue 3: per-row dot with Wc2, 16-lane reduce, cross-wave via Ms
        float bv[4], wv[4];
#pragma unroll
        for (int n = 0; n < 4; ++n) {
            int col = w * 64 + n * 16 + lr;
            bv[n] = bc1[col];
            wv[n] = Wc2[col];
        }
#pragma unroll
        for (int m = 0; m < 4; ++m)
#pragma unroll
            for (int r = 0; r < 4; ++r) {
                float p = 0.f;
#pragma unroll
                for (int n = 0; n < 4; ++n)
                    p += fmaxf(acc[m][n][r] + bv[n], 0.f) * wv[n];
                p += __shfl_xor(p, 1);
                p += __shfl_xor(p, 2);
                p += __shfl_xor(p, 4);
                p += __shfl_xor(p, 8);
                if (lr == 0) Ms[m * 16 + lq * 4 + r][w] = p;
            }
    }
    __syncthreads();

    // ---- coord scatter: csum[node][i] += cdiff[i] * m ----
    if (tid < 64) {
        float mval = Ms[tid][0] + Ms[tid][1] + Ms[tid][2] + Ms[tid][3];
        int e = (blockRow + tid) & (EE - 1);
        int node = tt * NN + rows[e];
#pragma unroll
        for (int i = 0; i < 12; ++i)
            atomicAdd(&csum[(size_t)node * 12 + i], CDs[tid][i] * mval);
    }

    // ---- agg scatter: aggf[node][col] += E2[row][col] (fire-and-forget tail) ----
#pragma unroll 4
    for (int i = 0; i < 64; ++i) {
        int e = (blockRow + i) & (EE - 1);
        int node = tt * NN + rows[e];
        float v = b2f(Es[i * 256 + (tid ^ ((i & 7) << 3))]);
        atomicAdd(&aggf[(size_t)node * 256 + tid], v);
    }
}

// ---------------- node GEMM (128x128, BK=32, proven structure) ----------------
// EPI 0: relu -> bf16 store.  EPI 2: f32 store outf = acc + bias + resid.
template<int EPI>
__global__ __launch_bounds__(256) void node_gemm_kernel(
    const unsigned short* __restrict__ A, const unsigned short* __restrict__ Wt,
    const float* __restrict__ bias, unsigned short* __restrict__ Cb, int KPAD,
    const float* __restrict__ resid, float* __restrict__ outf) {
    __shared__ unsigned short As[128 * 32];
    __shared__ unsigned short Bs[128 * 32];
    int tid = threadIdx.x;
    int lane = tid & 63, w = tid >> 6;
    int wr = w >> 1, wc = w & 1;
    int blockRow = blockIdx.x * 128, colBase = blockIdx.y * 128;
    int l4 = lane >> 2;
    int seg = lane & 3;

    int ar0 = blockRow + w * 16 + l4;
    int br0 = colBase + w * 16 + l4;
    const unsigned short* pA0 = A + (size_t)ar0 * KPAD + seg * 8;
    const unsigned short* pA1 = pA0 + (size_t)64 * KPAD;
    const unsigned short* pB0 = Wt + (size_t)br0 * KPAD + seg * 8;
    const unsigned short* pB1 = pB0 + (size_t)64 * KPAD;

    unsigned short* ldsA = As + w * 512;
    unsigned short* ldsB = Bs + w * 512;

    f32x4 acc[4][4] = {};
    int lr = lane & 15, lq = lane >> 4;

    for (int k0 = 0; k0 < KPAD; k0 += 32) {
        GLOAD_LDS16(pA0 + k0, ldsA);
        GLOAD_LDS16(pA1 + k0, ldsA + 2048);
        GLOAD_LDS16(pB0 + k0, ldsB);
        GLOAD_LDS16(pB1 + k0, ldsB + 2048);
        __syncthreads();
        bf16x8 a[4], b[4];
#pragma unroll
        for (int m = 0; m < 4; ++m)
            a[m] = *reinterpret_cast<const bf16x8*>(
                As + (wr * 64 + m * 16 + lr) * 32 + lq * 8);
#pragma unroll
        for (int n = 0; n < 4; ++n)
            b[n] = *reinterpret_cast<const bf16x8*>(
                Bs + (wc * 64 + n * 16 + lr) * 32 + lq * 8);
#pragma unroll
        for (int m = 0; m < 4; ++m)
#pragma unroll
            for (int n = 0; n < 4; ++n)
                acc[m][n] = __builtin_amdgcn_mfma_f32_16x16x32_bf16(
                    a[m], b[n], acc[m][n], 0, 0, 0);
        __syncthreads();
    }

    float bv[4];
#pragma unroll
    for (int n = 0; n < 4; ++n) bv[n] = bias[colBase + wc * 64 + n * 16 + lr];

#pragma unroll
    for (int m = 0; m < 4; ++m)
#pragma unroll
        for (int r = 0; r < 4; ++r) {
            int row = blockRow + wr * 64 + m * 16 + lq * 4 + r;
#pragma unroll
            for (int n = 0; n < 4; ++n) {
                int col = colBase + wc * 64 + n * 16 + lr;
                float v = acc[m][n][r] + bv[n];
                if (EPI == 2) {
                    outf[(size_t)row * 256 + col] =
                        v + resid[(size_t)row * 256 + col];
                } else {
                    Cb[(size_t)row * 256 + col] = f2b(fmaxf(v, 0.f));
                }
            }
        }
}

// node_in[nf][768] = [others(256), h(256), agg(256)] bf16
__global__ void nodein_kernel(const unsigned short* __restrict__ ob,
                              const unsigned short* __restrict__ hb,
                              const float* __restrict__ aggf,
                              unsigned short* __restrict__ node_in) {
    int idx = blockIdx.x * blockDim.x + threadIdx.x;
    int stride = gridDim.x * blockDim.x;
    const int total = TT * NN * 192;
    for (; idx < total; idx += stride) {
        int nf = idx / 192, c4 = (idx - nf * 192) * 4;
        ushort4 v;
        if (c4 < 256) {
            v = *reinterpret_cast<const ushort4*>(ob + (size_t)nf * 256 + c4);
        } else if (c4 < 512) {
            v = *reinterpret_cast<const ushort4*>(hb + (size_t)nf * 256 + (c4 - 256));
        } else {
            float4 a = *reinterpret_cast<const float4*>(aggf + (size_t)nf * 256 + (c4 - 512));
            v.x = f2b(a.x); v.y = f2b(a.y); v.z = f2b(a.z); v.w = f2b(a.w);
        }
        *reinterpret_cast<ushort4*>(node_in + (size_t)nf * 768 + c4) = v;
    }
}

__global__ void coordout_kernel(const float* __restrict__ x, const int* __restrict__ counts,
                                const float* __restrict__ csum, float* __restrict__ outc) {
    int idx = blockIdx.x * blockDim.x + threadIdx.x;
    if (idx >= TT * NN * 12) return;
    int n = (idx / 12) & (NN - 1);
    float cnt = (float)(counts[n] > 0 ? counts[n] : 1);
    outc[idx] = x[idx] + csum[idx] / cnt;
}

// ---------------- launch ----------------

extern "C" void kernel_launch(void* const* d_in, const int* in_sizes, int n_in,
                              void* d_out, int out_size, void* d_ws, size_t ws_size,
                              hipStream_t stream) {
    const float* x = (const float*)d_in[0];
    const float* h = (const float*)d_in[1];
    const float* others = (const float*)d_in[2];
    const float* We1 = (const float*)d_in[3];
    const float* be1 = (const float*)d_in[4];
    const float* We2 = (const float*)d_in[5];
    const float* be2 = (const float*)d_in[6];
    const float* Wn1 = (const float*)d_in[7];
    const float* bn1 = (const float*)d_in[8];
    const float* Wn2 = (const float*)d_in[9];
    const float* bn2 = (const float*)d_in[10];
    const float* Wc1 = (const float*)d_in[11];
    const float* bc1 = (const float*)d_in[12];
    const float* Wc2 = (const float*)d_in[13];
    const int* ei = (const int*)d_in[14];
    const int* rows = ei;
    const int* cols = ei + EE;

    char* wsb = (char*)d_ws;
    size_t off = 0;
    auto alloc = [&](size_t bytes) {
        void* p = wsb + off;
        off = (off + bytes + 255) & ~(size_t)255;
        return p;
    };
    const int TNH = TT * NN * HH;
    unsigned short* hb = (unsigned short*)alloc((size_t)TNH * 2);
    unsigned short* ob = (unsigned short*)alloc((size_t)TNH * 2);
    unsigned short* We1t = (unsigned short*)alloc(256 * 576 * 2);
    unsigned short* We2t = (unsigned short*)alloc(256 * 256 * 2);
    unsigned short* Wn1t = (unsigned short*)alloc(256 * 768 * 2);
    unsigned short* Wn2t = (unsigned short*)alloc(256 * 256 * 2);
    unsigned short* Wc1t = (unsigned short*)alloc(256 * 256 * 2);
    float* aggf = (float*)alloc((size_t)TT * NN * 256 * 4);  // contiguous zero region:
    float* csum = (float*)alloc((size_t)TT * NN * 12 * 4);   // aggf | csum | counts
    int* counts = (int*)alloc((size_t)NN * 4);
    unsigned short* node_in = (unsigned short*)alloc((size_t)TT * NN * 768 * 2);
    unsigned short* Z = (unsigned short*)alloc((size_t)TT * NN * 256 * 2);
    (void)ws_size;

    // ---- setup ----
    cvt_bf16_kernel<<<2048, 256, 0, stream>>>(h, hb, TNH);
    cvt_bf16_kernel<<<2048, 256, 0, stream>>>(others, ob, TNH);
    transpose_w_kernel<<<576, 256, 0, stream>>>(We1, We1t, 528, 576);
    transpose_w_kernel<<<256, 256, 0, stream>>>(We2, We2t, 256, 256);
    transpose_w_kernel<<<768, 256, 0, stream>>>(Wn1, Wn1t, 768, 768);
    transpose_w_kernel<<<256, 256, 0, stream>>>(Wn2, Wn2t, 256, 256);
    transpose_w_kernel<<<256, 256, 0, stream>>>(Wc1, Wc1t, 256, 256);
    zero_f32_kernel<<<2048, 256, 0, stream>>>(
        aggf, TT * NN * 256 + TT * NN * 12 + NN);  // aggf+csum+counts
    count_kernel<<<EE / 256, 256, 0, stream>>>(rows, counts);

    float* houtf = (float*)d_out;
    float* coutf = (float*)d_out + (size_t)TT * NN * HH;

    // ---- fused edge pipeline: all T at once ----
    edge_mega_kernel<<<TT * EE / 64, 256, 0, stream>>>(
        x, hb, We1t, be1, We2t, be2, Wc1t, bc1, Wc2, rows, cols, aggf, csum);

    // ---- node pipeline ----
    nodein_kernel<<<2048, 256, 0, stream>>>(ob, hb, aggf, node_in);
    node_gemm_kernel<0><<<dim3(TT * NN / 128, 2), 256, 0, stream>>>(
        node_in, Wn1t, bn1, Z, 768, nullptr, nullptr);
    node_gemm_kernel<2><<<dim3(TT * NN / 128, 2), 256, 0, stream>>>(
        Z, Wn2t, bn2, nullptr, 256, h, houtf);

    coordout_kernel<<<(TT * NN * 12 + 255) / 256, 256, 0, stream>>>(
        x, counts, csum, coutf);
}